// Round 5
// baseline (1385.607 us; speedup 1.0000x reference)
//
#include <hip/hip_runtime.h>

#define B_ 64
#define T_ 128
#define D_ 1024
#define K2_ 2048
#define G_ 4096

typedef __attribute__((ext_vector_type(8))) short bf16x8;
typedef __attribute__((ext_vector_type(4))) float f32x4;
typedef unsigned short u16;
typedef unsigned long long u64;

__device__ __forceinline__ u16 f2bf(float f) {
  unsigned int u = __float_as_uint(f);
  u += 0x7FFF + ((u >> 16) & 1);   // round-to-nearest-even
  return (u16)(u >> 16);
}

__device__ __forceinline__ float fast_sigmoid(float x) {
  return 1.f / (1.f + __expf(-x));
}
__device__ __forceinline__ float fast_tanh(float x) {
  float e = __expf(-2.f * fabsf(x));
  float t = (1.f - e) / (1.f + e);
  return copysignf(t, x);
}

// Coherent (cross-XCD) 16B load as two agent-scope relaxed atomic u64 loads:
// compiles to global_load_dwordx2 sc0 sc1 (L1+L2 bypass, served at IF).
__device__ __forceinline__ bf16x8 load_coh16(const u16* p) {
  union { u64 q[2]; bf16x8 v; } u;
  u.q[0] = __hip_atomic_load((u64*)p,       __ATOMIC_RELAXED, __HIP_MEMORY_SCOPE_AGENT);
  u.q[1] = __hip_atomic_load((u64*)(p + 4), __ATOMIC_RELAXED, __HIP_MEMORY_SCOPE_AGENT);
  return u.v;
}

// Pair-pack two adjacent bf16 (tid even = low half) and store 4B coherent.
__device__ __forceinline__ void store_pair_coh(u16* base, size_t soff, u16 v, int tid) {
  unsigned other = __shfl_xor((unsigned)v, 1);
  if (!(tid & 1))
    __hip_atomic_store((unsigned*)(base + soff), (unsigned)v | (other << 16),
                       __ATOMIC_RELAXED, __HIP_MEMORY_SCOPE_AGENT);
}

// Wt[n][k] = bf16(W[k][n]);  W:[2048][4096] f32, Wt:[4096][2048] bf16
__global__ __launch_bounds__(256) void transpose_w(const float* __restrict__ W,
                                                   u16* __restrict__ Wt) {
  __shared__ u16 tile[64][65];
  int bn = blockIdx.x & 63;
  int bk = blockIdx.x >> 6;
  int n0 = bn * 64, k0 = bk * 64;
  for (int i = threadIdx.x; i < 4096; i += 256) {
    int r = i >> 6, c = i & 63;
    tile[c][r] = f2bf(W[(size_t)(k0 + r) * G_ + n0 + c]);
  }
  __syncthreads();
  for (int i = threadIdx.x; i < 4096; i += 256) {
    int r = i >> 6, c = i & 63;
    Wt[(size_t)(n0 + r) * K2_ + k0 + c] = tile[r][c];
  }
}

// xg[(t*B+b)*D + d] = bf16(emb[inputs[b][t]][d])
__global__ __launch_bounds__(256) void gather_x(const int* __restrict__ inputs,
                                                const float* __restrict__ emb,
                                                u16* __restrict__ xg) {
  int idx = blockIdx.x * 256 + threadIdx.x;
  int d4 = idx & 255;
  int tb = idx >> 8;
  int t = tb >> 6, b = tb & 63;
  int tok = inputs[b * T_ + t];
  float4 v = ((const float4*)(emb + (size_t)tok * D_))[d4];
  u64 pk = (u64)f2bf(v.x)
         | ((u64)f2bf(v.y) << 16)
         | ((u64)f2bf(v.z) << 32)
         | ((u64)f2bf(v.w) << 48);
  *(u64*)(xg + (size_t)tb * D_ + d4 * 4) = pk;
}

__global__ void zero_buf(uint4* p, int n) {
  int i = blockIdx.x * blockDim.x + threadIdx.x;
  if (i < n) p[i] = make_uint4(0u, 0u, 0u, 0u);
}

template<bool COH>
__device__ __forceinline__ void gemm_half(const u16* a0p, const bf16x8 (&wreg)[4][8],
                                          f32x4 (&acc)[2][4]) {
  #pragma unroll
  for (int ks = 0; ks < 8; ++ks) {
    bf16x8 a0, a1;
    if (COH) {
      a0 = load_coh16(a0p + ks * 32);
      a1 = load_coh16(a0p + 16 * D_ + ks * 32);
    } else {
      a0 = *(const bf16x8*)(a0p + ks * 32);
      a1 = *(const bf16x8*)(a0p + 16 * D_ + ks * 32);
    }
    #pragma unroll
    for (int g = 0; g < 4; ++g) {
      acc[0][g] = __builtin_amdgcn_mfma_f32_16x16x32_bf16(a0, wreg[g][ks], acc[0][g], 0, 0, 0);
      acc[1][g] = __builtin_amdgcn_mfma_f32_16x16x32_bf16(a1, wreg[g][ks], acc[1][g], 0, 0, 0);
    }
  }
}

// Persistent pipelined 2-layer LSTM. 256 blocks x 512 threads, 1 block/CU.
// Blocks [0,128): layer 1 (t=i); [128,256): layer 2 (t=i-1).
// h-rings via sc0/sc1 agent-relaxed atomics (no fences, caches stay warm).
// Weights pinned in AGPRs. Single-level barrier: 16 lines/layer-iter,
// 8 arrivals each; wave 0 polls own + cross-layer lines as a 32-lane gather.
__global__ __launch_bounds__(512, 2) void lstm_persist(
    const u16* __restrict__ wt1, const u16* __restrict__ wt2,
    const u16* __restrict__ xg,
    u16* __restrict__ h1n, u16* __restrict__ h1buf, u16* __restrict__ h2buf,
    const float* __restrict__ b1, const float* __restrict__ b2,
    const int* __restrict__ lens, float* __restrict__ out,
    int* bar) {
  __shared__ __attribute__((aligned(16))) float part[8][64][36];
  __shared__ __attribute__((aligned(16))) float gsum[64][36];
  const int blk = blockIdx.x;
  const int L = blk >> 7;
  const int lb = blk & 127;
  const int rg = lb & 1;
  const int cg = lb >> 1;
  const int tid = threadIdx.x;
  const int lane = tid & 63;
  const int wv = tid >> 6;
  const int dc = lane & 15;
  const int kq = lane >> 4;

  const u16* wt = L ? wt2 : wt1;
  const float* bias = L ? b2 : b1;

  // register-resident weights: 4 gates x 8 k-steps of bf16x8 = 128 regs,
  // pinned to the AGPR file (legal MFMA B-operand bank on gfx950).
  bf16x8 wreg[4][8];
  {
    const u16* wb = wt + (size_t)(cg * 16 + dc) * K2_ + wv * 256 + kq * 8;
    #pragma unroll
    for (int g = 0; g < 4; ++g)
      #pragma unroll
      for (int ks = 0; ks < 8; ++ks)
        wreg[g][ks] = *(const bf16x8*)(wb + (size_t)g * D_ * K2_ + ks * 32);
  }
  #pragma unroll
  for (int g = 0; g < 4; ++g)
    #pragma unroll
    for (int ks = 0; ks < 8; ++ks)
      asm volatile("" : "+a"(wreg[g][ks]));   // pin in AGPRs: resident, no reload

  const int crow = tid >> 4;          // 0..31
  const int cdc = tid & 15;
  const int grow = rg * 32 + crow;
  const int dcol = cg * 16 + cdc;
  const int len_r = lens[grow];
  float bias_g[4];
  #pragma unroll
  for (int g = 0; g < 4; ++g) bias_g[g] = bias[g * D_ + dcol];
  float creg = 0.f, hreg = 0.f, outreg = 0.f;

  const int r0 = rg * 32 + (lane & 15);
  const int koff = (wv & 3) * 256 + kq * 8;

  for (int i = 0; i <= 128; ++i) {
    const bool active = L ? (i >= 1) : (i < 128);
    const int t = L ? i - 1 : i;
    if (active) {
      f32x4 acc[2][4];
      #pragma unroll
      for (int rt = 0; rt < 2; ++rt)
        #pragma unroll
        for (int g = 0; g < 4; ++g)
          acc[rt][g] = (f32x4){0.f, 0.f, 0.f, 0.f};

      if (L == 0 && wv < 4) {
        const u16* a0p = xg + (size_t)t * (B_ * D_) + (size_t)r0 * D_ + koff;
        gemm_half<false>(a0p, wreg, acc);
      } else {
        const u16* src;
        if (L == 0)
          src = h1buf + (size_t)((i + 3) & 3) * (B_ * D_);
        else
          src = (wv < 4) ? h1n + (size_t)((i + 3) & 3) * (B_ * D_)
                         : h2buf + (size_t)((i + 2) & 3) * (B_ * D_);
        gemm_half<true>(src + (size_t)r0 * D_ + koff, wreg, acc);
      }

      // partials to LDS: D-layout col = lane&15, row = kq*4 + r
      #pragma unroll
      for (int rt = 0; rt < 2; ++rt)
        #pragma unroll
        for (int g = 0; g < 4; ++g)
          *(f32x4*)&part[wv][g * 16 + dc][rt * 16 + kq * 4] = acc[rt][g];
      __syncthreads();

      // 8-way k-reduction
      {
        const int rcol = tid >> 3;
        const int rrow = (tid & 7) * 4;
        f32x4 s = *(const f32x4*)&part[0][rcol][rrow];
        #pragma unroll
        for (int w = 1; w < 8; ++w) s += *(const f32x4*)&part[w][rcol][rrow];
        *(f32x4*)&gsum[rcol][rrow] = s;
      }
      __syncthreads();

      // fused LSTM cell, one element per thread
      {
        float gi = gsum[cdc][crow] + bias_g[0];
        float gj = gsum[16 + cdc][crow] + bias_g[1];
        float gf = gsum[32 + cdc][crow] + bias_g[2];
        float go = gsum[48 + cdc][crow] + bias_g[3];
        float is = fast_sigmoid(gi);
        float fs = fast_sigmoid(gf);
        float os = fast_sigmoid(go);
        float jt = fast_tanh(gj);
        float c_new = creg * fs + is * jt;
        float h_new = fast_tanh(c_new) * os;
        bool m = t < len_r;
        if (m) { creg = c_new; hreg = h_new; }
        size_t soff = (size_t)grow * D_ + dcol;
        if (L == 0) {
          store_pair_coh(h1n  + (size_t)(i & 3) * (B_ * D_), soff, f2bf(h_new), tid);
          store_pair_coh(h1buf + (size_t)(i & 3) * (B_ * D_), soff, f2bf(hreg), tid);
        } else {
          store_pair_coh(h2buf + (size_t)((i + 3) & 3) * (B_ * D_), soff, f2bf(hreg), tid);
          if (m) outreg += h_new;
        }
      }
    }

    if (i < 128) {
      // Single-level barrier. __syncthreads drains vmcnt per wave, so all
      // sc1 stores are at the coherence point before tid0 signals arrival.
      __syncthreads();
      if (tid == 0)
        __hip_atomic_fetch_add(bar + (size_t)((L * 128 + i) * 16 + (lb >> 3)) * 32, 1,
                               __ATOMIC_RELAXED, __HIP_MEMORY_SCOPE_AGENT);
      if (tid < 32) {
        // lanes 0-15: own layer @ i.  lanes 16-31: cross-layer dependency
        // (L2 waits L1@i for h1n; L1 waits L2@i-2 for ring anti-clobber).
        bool need = true;
        int li;
        if (tid < 16) li = (L * 128 + i) * 16 + tid;
        else if (L == 1) li = i * 16 + (tid - 16);
        else { need = (i >= 2); li = (128 + i - 2) * 16 + (tid - 16); }
        if (need) {
          const int* line = bar + (size_t)li * 32;
          while (__hip_atomic_load(line, __ATOMIC_RELAXED, __HIP_MEMORY_SCOPE_AGENT) < 8)
            __builtin_amdgcn_s_sleep(1);
        }
      }
      __syncthreads();
    }
  }
  if (L == 1) out[(size_t)grow * D_ + dcol] = outreg;
}

extern "C" void kernel_launch(void* const* d_in, const int* in_sizes, int n_in,
                              void* d_out, int out_size, void* d_ws, size_t ws_size,
                              hipStream_t stream) {
  const int* inputs  = (const int*)d_in[0];
  const int* lengths = (const int*)d_in[1];
  const float* emb   = (const float*)d_in[2];
  const float* W1    = (const float*)d_in[3];
  const float* b1    = (const float*)d_in[4];
  const float* W2    = (const float*)d_in[5];
  const float* b2    = (const float*)d_in[6];
  float* out = (float*)d_out;

  // workspace carve (~50 MiB)
  char* p = (char*)d_ws;
  u16* wt1   = (u16*)p; p += (size_t)G_ * K2_ * 2;        // 16 MiB
  u16* wt2   = (u16*)p; p += (size_t)G_ * K2_ * 2;        // 16 MiB
  u16* xg    = (u16*)p; p += (size_t)T_ * B_ * D_ * 2;    // 16 MiB
  u16* h1n   = (u16*)p; p += (size_t)4 * B_ * D_ * 2;     // 512 KiB ring
  u16* h1buf = (u16*)p; p += (size_t)4 * B_ * D_ * 2;     // 512 KiB ring
  u16* h2buf = (u16*)p; p += (size_t)4 * B_ * D_ * 2;     // 512 KiB ring
  int* bar   = (int*)p; p += (size_t)2 * 128 * 16 * 32 * 4; // 512 KiB

  hipLaunchKernelGGL(transpose_w, dim3(2048), dim3(256), 0, stream, W1, wt1);
  hipLaunchKernelGGL(transpose_w, dim3(2048), dim3(256), 0, stream, W2, wt2);
  hipLaunchKernelGGL(gather_x, dim3(8192), dim3(256), 0, stream, inputs, emb, xg);
  // zero rings + barrier lines contiguously:
  // 3*524288 + 524288 = 2,097,152 B = 131,072 uint4
  hipLaunchKernelGGL(zero_buf, dim3(512), dim3(256), 0, stream, (uint4*)h1n, 131072);

  hipLaunchKernelGGL(lstm_persist, dim3(256), dim3(512), 0, stream,
                     wt1, wt2, xg, h1n, h1buf, h2buf, b1, b2, lengths, out, bar);
}

// Round 6
// 921.231 us; speedup vs baseline: 1.5041x; 1.5041x over previous
//
#include <hip/hip_runtime.h>

#define B_ 64
#define T_ 128
#define D_ 1024
#define K2_ 2048
#define G_ 4096
#define SLOTW 65664   // u16 per ring slot: 128 KiB payload + 256 B anti-prefetch pad

typedef __attribute__((ext_vector_type(8))) short bf16x8;
typedef __attribute__((ext_vector_type(4))) float f32x4;
typedef unsigned short u16;
typedef unsigned long long u64;

__device__ __forceinline__ u16 f2bf(float f) {
  unsigned int u = __float_as_uint(f);
  u += 0x7FFF + ((u >> 16) & 1);   // round-to-nearest-even
  return (u16)(u >> 16);
}

__device__ __forceinline__ float fast_sigmoid(float x) {
  return 1.f / (1.f + __expf(-x));
}
__device__ __forceinline__ float fast_tanh(float x) {
  float e = __expf(-2.f * fabsf(x));
  float t = (1.f - e) / (1.f + e);
  return copysignf(t, x);
}

// Write-through store (sc0 sc1): lands at IF, never dirty in any L2, so
// plain cached loads of this (never-reused) address are safe everywhere.
__device__ __forceinline__ void store4_wt(u16* addr, unsigned v) {
  asm volatile("global_store_dword %0, %1, off sc0 sc1"
               :: "v"((void*)addr), "v"(v) : "memory");
}

// Pair-pack two adjacent bf16 (even tid = low half) and store 4B write-through.
__device__ __forceinline__ void store_pair_wt(u16* base, size_t soff, u16 v, int tid) {
  unsigned other = __shfl_xor((unsigned)v, 1);
  if (!(tid & 1))
    store4_wt(base + soff, (unsigned)v | (other << 16));
}

// Wt[n][k] = bf16(W[k][n]);  W:[2048][4096] f32, Wt:[4096][2048] bf16
__global__ __launch_bounds__(256) void transpose_w(const float* __restrict__ W,
                                                   u16* __restrict__ Wt) {
  __shared__ u16 tile[64][65];
  int bn = blockIdx.x & 63;
  int bk = blockIdx.x >> 6;
  int n0 = bn * 64, k0 = bk * 64;
  for (int i = threadIdx.x; i < 4096; i += 256) {
    int r = i >> 6, c = i & 63;
    tile[c][r] = f2bf(W[(size_t)(k0 + r) * G_ + n0 + c]);
  }
  __syncthreads();
  for (int i = threadIdx.x; i < 4096; i += 256) {
    int r = i >> 6, c = i & 63;
    Wt[(size_t)(n0 + r) * K2_ + k0 + c] = tile[r][c];
  }
}

// xg[(t*B+b)*D + d] = bf16(emb[inputs[b][t]][d])
__global__ __launch_bounds__(256) void gather_x(const int* __restrict__ inputs,
                                                const float* __restrict__ emb,
                                                u16* __restrict__ xg) {
  int idx = blockIdx.x * 256 + threadIdx.x;
  int d4 = idx & 255;
  int tb = idx >> 8;
  int t = tb >> 6, b = tb & 63;
  int tok = inputs[b * T_ + t];
  float4 v = ((const float4*)(emb + (size_t)tok * D_))[d4];
  u64 pk = (u64)f2bf(v.x)
         | ((u64)f2bf(v.y) << 16)
         | ((u64)f2bf(v.z) << 32)
         | ((u64)f2bf(v.w) << 48);
  *(u64*)(xg + (size_t)tb * D_ + d4 * 4) = pk;
}

__global__ void zero_buf(uint4* p, int n) {
  int i = blockIdx.x * blockDim.x + threadIdx.x;
  if (i < n) p[i] = make_uint4(0u, 0u, 0u, 0u);
}

// --- barrier helpers: 128-B lines, agent-relaxed atomics only ---
// per-layer-iter line group: 8 cnt lines (16 arrivals) + root(8) + done.
__device__ __forceinline__ void arrive_dev(int* bar, int lineBase, int lb) {
  int a = __hip_atomic_fetch_add(bar + (size_t)(lineBase + (lb & 7)) * 32, 1,
                                 __ATOMIC_RELAXED, __HIP_MEMORY_SCOPE_AGENT);
  if (a == 15) {
    int r = __hip_atomic_fetch_add(bar + (size_t)(lineBase + 8) * 32, 1,
                                   __ATOMIC_RELAXED, __HIP_MEMORY_SCOPE_AGENT);
    if (r == 7)
      __hip_atomic_store(bar + (size_t)(lineBase + 9) * 32, 1,
                         __ATOMIC_RELAXED, __HIP_MEMORY_SCOPE_AGENT);
  }
}
__device__ __forceinline__ void waitdone_dev(int* bar, int lineBase) {
  while (!__hip_atomic_load(bar + (size_t)(lineBase + 9) * 32,
                            __ATOMIC_RELAXED, __HIP_MEMORY_SCOPE_AGENT))
    __builtin_amdgcn_s_sleep(1);
}
#define LINEOF(L, i) (10 + ((L) * 129 + (i)) * 10)

// Persistent pipelined 2-layer LSTM. 256 blocks x 512 threads, 1 block/CU.
// Blocks [0,128): layer 1 (t=i, i in [0,128)); [128,256): layer 2 (t=i-1).
// T-deep h rings (unique address per step): producers store write-through
// (sc0 sc1), consumers use PLAIN CACHED loads -> per-XCD L2 absorbs the 64x
// h-broadcast. One startup grid barrier + one agent-acquire fence kills the
// wt-alias lines; no fences in the main loop.
__global__ __launch_bounds__(512, 2) void lstm_persist(
    const u16* wt1, const u16* wt2,
    const u16* __restrict__ xg,
    u16* h1buf, u16* h1n, u16* h2buf,
    const u16* __restrict__ zbuf,
    const float* __restrict__ b1, const float* __restrict__ b2,
    const int* __restrict__ lens, float* __restrict__ out,
    int* bar) {
  __shared__ __attribute__((aligned(16))) float part[8][64][36];
  __shared__ __attribute__((aligned(16))) float gsum[64][36];
  const int blk = blockIdx.x;
  const int L = blk >> 7;
  const int lb = blk & 127;
  const int rg = lb & 1;
  const int cg = lb >> 1;
  const int tid = threadIdx.x;
  const int lane = tid & 63;
  const int wv = tid >> 6;
  const int dc = lane & 15;
  const int kq = lane >> 4;

  const u16* wt = L ? wt2 : wt1;
  const float* bias = L ? b2 : b1;

  // register-resident weights: 4 gates x 8 k-steps of bf16x8 = 128 regs
  bf16x8 wreg[4][8];
  {
    const u16* wb = wt + (size_t)(cg * 16 + dc) * K2_ + wv * 256 + kq * 8;
    #pragma unroll
    for (int g = 0; g < 4; ++g)
      #pragma unroll
      for (int ks = 0; ks < 8; ++ks)
        wreg[g][ks] = *(const bf16x8*)(wb + (size_t)g * D_ * K2_ + ks * 32);
  }
  #pragma unroll
  for (int g = 0; g < 4; ++g)
    #pragma unroll
    for (int ks = 0; ks < 8; ++ks)
      asm volatile("" : "+v"(wreg[g][ks]));   // pin: no reload inside loop

  const int crow = tid >> 4;          // 0..31
  const int cdc = tid & 15;
  const int grow = rg * 32 + crow;
  const int dcol = cg * 16 + cdc;
  const int len_r = lens[grow];
  float bias_g[4];
  #pragma unroll
  for (int g = 0; g < 4; ++g) bias_g[g] = bias[g * D_ + dcol];
  float creg = 0.f, hreg = 0.f, outreg = 0.f;

  const int r0 = rg * 32 + (lane & 15);
  const int koff = (wv & 3) * 256 + kq * 8;

  // ---- startup grid barrier (all 256 blocks; weights loaded before any
  // ring write can alias them), then one-time L1/L2 invalidate ----
  __syncthreads();
  if (tid == 0) {
    int a = __hip_atomic_fetch_add(bar + (size_t)(blk & 7) * 32, 1,
                                   __ATOMIC_RELAXED, __HIP_MEMORY_SCOPE_AGENT);
    if (a == 31) {
      int r = __hip_atomic_fetch_add(bar + 8 * 32, 1,
                                     __ATOMIC_RELAXED, __HIP_MEMORY_SCOPE_AGENT);
      if (r == 7)
        __hip_atomic_store(bar + 9 * 32, 1,
                           __ATOMIC_RELAXED, __HIP_MEMORY_SCOPE_AGENT);
    }
    while (!__hip_atomic_load(bar + 9 * 32,
                              __ATOMIC_RELAXED, __HIP_MEMORY_SCOPE_AGENT))
      __builtin_amdgcn_s_sleep(1);
  }
  __syncthreads();
  __builtin_amdgcn_fence(__ATOMIC_ACQUIRE, "agent");  // inv stale wt-alias lines

  for (int i = 0; i <= 128; ++i) {
    const bool active = L ? (i >= 1) : (i < 128);
    const int t = L ? i - 1 : i;
    if (active) {
      // top-of-iteration dependency waits
      if (tid == 0) {
        if (L == 0) {
          if (i >= 1) waitdone_dev(bar, LINEOF(0, i - 1));   // own h1buf(i-1)
        } else {
          waitdone_dev(bar, LINEOF(0, i - 1));               // h1n(i-1) ready
          if (i >= 2) waitdone_dev(bar, LINEOF(1, i - 1));   // own h2buf(i-2)
        }
      }
      __syncthreads();

      // per-iteration source/destination slots (plain cached loads!)
      const u16* xsrc; const u16* hsrc;
      u16* w_h1n = nullptr; u16* w_h1b = nullptr; u16* w_h2b = nullptr;
      if (L == 0) {
        xsrc = xg + (size_t)t * (B_ * D_);
        hsrc = (i == 0) ? zbuf : h1buf + (size_t)(i - 1) * SLOTW;
        w_h1n = h1n + (size_t)i * SLOTW;
        w_h1b = h1buf + (size_t)i * SLOTW;
      } else {
        xsrc = h1n + (size_t)(i - 1) * SLOTW;
        hsrc = (i <= 1) ? zbuf : h2buf + (size_t)(i - 2) * SLOTW;
        w_h2b = h2buf + (size_t)(i - 1) * SLOTW;
      }
      const u16* src = (wv < 4) ? xsrc : hsrc;
      const u16* a0p = src + (size_t)r0 * D_ + koff;

      f32x4 acc[2][4];
      #pragma unroll
      for (int rt = 0; rt < 2; ++rt)
        #pragma unroll
        for (int g = 0; g < 4; ++g)
          acc[rt][g] = (f32x4){0.f, 0.f, 0.f, 0.f};

      #pragma unroll
      for (int ks = 0; ks < 8; ++ks) {
        bf16x8 a0 = *(const bf16x8*)(a0p + ks * 32);
        bf16x8 a1 = *(const bf16x8*)(a0p + 16 * D_ + ks * 32);
        #pragma unroll
        for (int g = 0; g < 4; ++g) {
          acc[0][g] = __builtin_amdgcn_mfma_f32_16x16x32_bf16(a0, wreg[g][ks], acc[0][g], 0, 0, 0);
          acc[1][g] = __builtin_amdgcn_mfma_f32_16x16x32_bf16(a1, wreg[g][ks], acc[1][g], 0, 0, 0);
        }
      }

      // partials to LDS: D-layout col = lane&15, row = kq*4 + r
      #pragma unroll
      for (int rt = 0; rt < 2; ++rt)
        #pragma unroll
        for (int g = 0; g < 4; ++g)
          *(f32x4*)&part[wv][g * 16 + dc][rt * 16 + kq * 4] = acc[rt][g];
      __syncthreads();

      // 8-way k-reduction
      {
        const int rcol = tid >> 3;
        const int rrow = (tid & 7) * 4;
        f32x4 s = *(const f32x4*)&part[0][rcol][rrow];
        #pragma unroll
        for (int w = 1; w < 8; ++w) s += *(const f32x4*)&part[w][rcol][rrow];
        *(f32x4*)&gsum[rcol][rrow] = s;
      }
      __syncthreads();

      // fused LSTM cell, one element per thread
      {
        float gi = gsum[cdc][crow] + bias_g[0];
        float gj = gsum[16 + cdc][crow] + bias_g[1];
        float gf = gsum[32 + cdc][crow] + bias_g[2];
        float go = gsum[48 + cdc][crow] + bias_g[3];
        float is = fast_sigmoid(gi);
        float fs = fast_sigmoid(gf);
        float os = fast_sigmoid(go);
        float jt = fast_tanh(gj);
        float c_new = creg * fs + is * jt;
        float h_new = fast_tanh(c_new) * os;
        bool m = t < len_r;
        if (m) { creg = c_new; hreg = h_new; }
        size_t soff = (size_t)grow * D_ + dcol;
        if (L == 0) {
          store_pair_wt(w_h1n, soff, f2bf(h_new), tid);   // raw h1n -> layer 2
          store_pair_wt(w_h1b, soff, f2bf(hreg), tid);    // masked state
        } else {
          store_pair_wt(w_h2b, soff, f2bf(hreg), tid);
          if (m) outreg += h_new;
        }
      }

      // drain write-through stores (per wave), then signal arrival
      asm volatile("s_waitcnt vmcnt(0)" ::: "memory");
      __syncthreads();
      if (tid == 0 && !(L == 1 && i == 128))
        arrive_dev(bar, LINEOF(L, i), lb);
    }
  }
  if (L == 1) out[(size_t)grow * D_ + dcol] = outreg;
}

extern "C" void kernel_launch(void* const* d_in, const int* in_sizes, int n_in,
                              void* d_out, int out_size, void* d_ws, size_t ws_size,
                              hipStream_t stream) {
  const int* inputs  = (const int*)d_in[0];
  const int* lengths = (const int*)d_in[1];
  const float* emb   = (const float*)d_in[2];
  const float* W1    = (const float*)d_in[3];
  const float* b1    = (const float*)d_in[4];
  const float* W2    = (const float*)d_in[5];
  const float* b2    = (const float*)d_in[6];
  float* out = (float*)d_out;

  // workspace carve (~64.5 MiB total; rings alias the one-shot wt buffers)
  char* p = (char*)d_ws;
  u16* h1buf = (u16*)p; p += (size_t)T_ * SLOTW * 2;   // 16.03 MiB (aliases wt1)
  u16* h1n   = (u16*)p; p += (size_t)T_ * SLOTW * 2;   // 16.03 MiB (aliases wt2)
  u16* h2buf = (u16*)p; p += (size_t)T_ * SLOTW * 2;   // 16.03 MiB
  u16* xg    = (u16*)p; p += (size_t)T_ * B_ * D_ * 2; // 16 MiB
  u16* zbuf  = (u16*)p; p += (size_t)B_ * D_ * 2;      // 128 KiB (zeros)
  int* bar   = (int*)p; p += 2590 * 128;               // 331.5 KiB barrier lines
  u16* wt1 = h1buf;   // weights read once, pre-startup-barrier
  u16* wt2 = h1n;

  hipLaunchKernelGGL(transpose_w, dim3(2048), dim3(256), 0, stream, W1, wt1);
  hipLaunchKernelGGL(transpose_w, dim3(2048), dim3(256), 0, stream, W2, wt2);
  hipLaunchKernelGGL(gather_x, dim3(8192), dim3(256), 0, stream, inputs, emb, xg);
  // zero zbuf + bar contiguously: (131072 + 331520)/16 = 28912 uint4
  hipLaunchKernelGGL(zero_buf, dim3(113), dim3(256), 0, stream, (uint4*)zbuf, 28912);

  hipLaunchKernelGGL(lstm_persist, dim3(256), dim3(512), 0, stream,
                     wt1, wt2, xg, h1buf, h1n, h2buf, zbuf, b1, b2, lengths, out,
                     bar);
}